// Round 1
// baseline (196.170 us; speedup 1.0000x reference)
//
#include <hip/hip_runtime.h>
#include <math.h>

// Problem constants
#define NHID 512
#define T_K  256
#define T_Q  128
#define BB   8

// 2*log2(e): tanh(x) = 1 - 2/(exp2(C*x)+1)
constexpr float C2L2E = 2.8853900817779268f;
constexpr float L2E   = 1.4426950408889634f;

__device__ __forceinline__ float fexp2(float x) { return __builtin_amdgcn_exp2f(x); }
__device__ __forceinline__ float frcp(float x)  { return __builtin_amdgcn_rcpf(x); }

// ---------------------------------------------------------------------------
// Kernel 1: fused projection GEMM.
// Rows 0..2047  : c_key rows  (k*8+b)  -> kp' = (ck @ W1[:512] + b1) * C2L2E
// Rows 2048..3071: query rows (q*8+b)  -> qp' = (q  @ W1[512:])      * C2L2E
// 64x64 tile, K-chunk 16, 256 threads, 4x4 acc per thread.
// ---------------------------------------------------------------------------
__global__ __launch_bounds__(256) void proj_kernel(
    const float* __restrict__ qry, const float* __restrict__ ckey,
    const float* __restrict__ W1, const float* __restrict__ b1,
    float* __restrict__ kp, float* __restrict__ qp)
{
    const int row0 = blockIdx.x * 64;   // 48 tiles
    const int col0 = blockIdx.y * 64;   // 8 tiles
    const bool isK = row0 < 2048;
    const float* __restrict__ A  = isK ? ckey : qry;
    const int arow0              = isK ? row0 : row0 - 2048;
    const float* __restrict__ Bm = isK ? W1 : (W1 + 512 * 512);

    __shared__ float As[16][64];
    __shared__ float Bs[16][64];

    const int t  = threadIdx.x;
    const int tx = t & 15, ty = t >> 4;

    float acc[4][4] = {};

    for (int k0 = 0; k0 < 512; k0 += 16) {
        // stage A: 64 rows x 16 k  (transpose into As[k][m])
        {
            const int r  = t >> 2;          // 0..63
            const int c4 = (t & 3) * 4;     // 0,4,8,12
            const float4 av = *(const float4*)&A[(arow0 + r) * 512 + k0 + c4];
            As[c4 + 0][r] = av.x; As[c4 + 1][r] = av.y;
            As[c4 + 2][r] = av.z; As[c4 + 3][r] = av.w;
            // stage B: 16 k x 64 cols
            const int kr  = t >> 4;         // 0..15
            const int c4b = (t & 15) * 4;   // 0..60
            *(float4*)&Bs[kr][c4b] = *(const float4*)&Bm[(k0 + kr) * 512 + col0 + c4b];
        }
        __syncthreads();
        #pragma unroll
        for (int kk = 0; kk < 16; ++kk) {
            const float4 a4 = *(const float4*)&As[kk][ty * 4];
            const float4 b4 = *(const float4*)&Bs[kk][tx * 4];
            const float a[4]  = {a4.x, a4.y, a4.z, a4.w};
            const float bb[4] = {b4.x, b4.y, b4.z, b4.w};
            #pragma unroll
            for (int i = 0; i < 4; ++i)
                #pragma unroll
                for (int j = 0; j < 4; ++j)
                    acc[i][j] = fmaf(a[i], bb[j], acc[i][j]);
        }
        __syncthreads();
    }

    const int col = col0 + tx * 4;
    const float4 bv = *(const float4*)&b1[col];
    #pragma unroll
    for (int i = 0; i < 4; ++i) {
        const int row = row0 + ty * 4 + i;
        float4 o;
        if (isK) {
            o.x = (acc[i][0] + bv.x) * C2L2E;
            o.y = (acc[i][1] + bv.y) * C2L2E;
            o.z = (acc[i][2] + bv.z) * C2L2E;
            o.w = (acc[i][3] + bv.w) * C2L2E;
            *(float4*)&kp[row * 512 + col] = o;
        } else {
            o.x = acc[i][0] * C2L2E; o.y = acc[i][1] * C2L2E;
            o.z = acc[i][2] * C2L2E; o.w = acc[i][3] * C2L2E;
            *(float4*)&qp[(row - 2048) * 512 + col] = o;
        }
    }
}

// ---------------------------------------------------------------------------
// Kernel 2: fused tanh-MLP attention scores (the 134M-tanh hot loop).
// Block: 256 thr = 4 waves; wave w handles q = blockIdx.x*4+w, fixed b,
// k-range of 128 (z-split 2). Lanes span H: lane holds h in
// {lane*4..+3} u {256+lane*4..+3} (conflict-free b128 LDS reads).
// score[k,q,b] = (sumW2 + b2) - 2 * sum_h W2[h] / (exp2(kp'+qp')+1), mask -> -inf
// Written to ws_score[(q*8+b)*256 + k] (k-contiguous for softmax).
// ---------------------------------------------------------------------------
__global__ __launch_bounds__(256) void score_kernel(
    const float* __restrict__ kp, const float* __restrict__ qp,
    const float* __restrict__ W2, const float* __restrict__ b2,
    const int* __restrict__ mask, float* __restrict__ score)
{
    const int b    = blockIdx.y;
    const int t    = threadIdx.x;
    const int wave = t >> 6, lane = t & 63;
    const int q    = blockIdx.x * 4 + wave;
    const int k0   = blockIdx.z * 128;

    const int hA = lane * 4;
    const int hB = 256 + lane * 4;

    const float4 qA = *(const float4*)&qp[(q * 8 + b) * 512 + hA];
    const float4 qB = *(const float4*)&qp[(q * 8 + b) * 512 + hB];
    const float4 wA = *(const float4*)&W2[hA];
    const float4 wB = *(const float4*)&W2[hB];

    // base = sum(W2) + b2  (wave-wide reduce, once)
    float s2 = wA.x + wA.y + wA.z + wA.w + wB.x + wB.y + wB.z + wB.w;
    #pragma unroll
    for (int m = 32; m; m >>= 1) s2 += __shfl_xor(s2, m, 64);
    const float base = s2 + b2[0];

    __shared__ float kps[8][512];

    for (int kc = 0; kc < 128; kc += 8) {
        __syncthreads();
        {   // stage kp rows [k0+kc .. +7] for this b: 8*512 floats
            const int r = t >> 5;            // 0..7
            const int c = (t & 31) * 16;     // 0..496
            const float* src = &kp[((size_t)(k0 + kc + r) * 8 + b) * 512 + c];
            float4 v0 = *(const float4*)&src[0];
            float4 v1 = *(const float4*)&src[4];
            float4 v2 = *(const float4*)&src[8];
            float4 v3 = *(const float4*)&src[12];
            *(float4*)&kps[r][c + 0]  = v0;
            *(float4*)&kps[r][c + 4]  = v1;
            *(float4*)&kps[r][c + 8]  = v2;
            *(float4*)&kps[r][c + 12] = v3;
        }
        __syncthreads();

        #pragma unroll
        for (int kk = 0; kk < 8; ++kk) {
            const float4 kA = *(const float4*)&kps[kk][hA];
            const float4 kB = *(const float4*)&kps[kk][hB];
            float racc;
            racc  = wA.x * frcp(fexp2(kA.x + qA.x) + 1.0f);
            racc  = fmaf(wA.y, frcp(fexp2(kA.y + qA.y) + 1.0f), racc);
            racc  = fmaf(wA.z, frcp(fexp2(kA.z + qA.z) + 1.0f), racc);
            racc  = fmaf(wA.w, frcp(fexp2(kA.w + qA.w) + 1.0f), racc);
            racc  = fmaf(wB.x, frcp(fexp2(kB.x + qB.x) + 1.0f), racc);
            racc  = fmaf(wB.y, frcp(fexp2(kB.y + qB.y) + 1.0f), racc);
            racc  = fmaf(wB.z, frcp(fexp2(kB.z + qB.z) + 1.0f), racc);
            racc  = fmaf(wB.w, frcp(fexp2(kB.w + qB.w) + 1.0f), racc);
            #pragma unroll
            for (int m = 32; m; m >>= 1) racc += __shfl_xor(racc, m, 64);
            if (lane == 0) {
                const int k = k0 + kc + kk;
                float sc = base - 2.0f * racc;
                if (mask[k * 8 + b]) sc = -INFINITY;
                score[(q * 8 + b) * 256 + k] = sc;
            }
        }
    }
}

// ---------------------------------------------------------------------------
// Kernel 3: softmax over k (256) per (q,b) column. One wave per (q,b).
// Writes att_prob to d_out ([k][q][b], scattered, tiny) and to ws_prob
// ([q*8+b][k], coalesced) for the ant_vec kernel.
// ---------------------------------------------------------------------------
__global__ __launch_bounds__(256) void softmax_kernel(
    const float* __restrict__ score, float* __restrict__ prob_out,
    float* __restrict__ prob_ws)
{
    const int t = threadIdx.x;
    const int wave = t >> 6, lane = t & 63;
    const int qb = blockIdx.x * 4 + wave;      // = q*8+b

    float4 s4 = *(const float4*)&score[qb * 256 + lane * 4];
    float m = fmaxf(fmaxf(s4.x, s4.y), fmaxf(s4.z, s4.w));
    #pragma unroll
    for (int d = 32; d; d >>= 1) m = fmaxf(m, __shfl_xor(m, d, 64));

    float4 p;
    p.x = fexp2((s4.x - m) * L2E);
    p.y = fexp2((s4.y - m) * L2E);
    p.z = fexp2((s4.z - m) * L2E);
    p.w = fexp2((s4.w - m) * L2E);
    float sum = p.x + p.y + p.z + p.w;
    #pragma unroll
    for (int d = 32; d; d >>= 1) sum += __shfl_xor(sum, d, 64);
    const float inv = frcp(sum);
    p.x *= inv; p.y *= inv; p.z *= inv; p.w *= inv;

    *(float4*)&prob_ws[qb * 256 + lane * 4] = p;

    const int q = qb >> 3, b = qb & 7;
    const int kbase = lane * 4;
    prob_out[(kbase + 0) * (T_Q * BB) + q * 8 + b] = p.x;
    prob_out[(kbase + 1) * (T_Q * BB) + q * 8 + b] = p.y;
    prob_out[(kbase + 2) * (T_Q * BB) + q * 8 + b] = p.z;
    prob_out[(kbase + 3) * (T_Q * BB) + q * 8 + b] = p.w;
}

// ---------------------------------------------------------------------------
// Kernel 4: ant_vec[q,b,h] = sum_k prob[k,q,b] * c_key[k,b,h].
// Block: 256 thr = one h-half (256 h), fixed b, 4 q's. Loop k by 4.
// ---------------------------------------------------------------------------
__global__ __launch_bounds__(256) void antvec_kernel(
    const float* __restrict__ ckey, const float* __restrict__ prob_ws,
    float* __restrict__ out)
{
    const int q0 = blockIdx.x * 4;             // 32 tiles
    const int b  = blockIdx.y;                 // 8
    const int h  = blockIdx.z * 256 + threadIdx.x;  // 2 halves

    float acc0 = 0.f, acc1 = 0.f, acc2 = 0.f, acc3 = 0.f;
    const float* p0 = &prob_ws[((q0 + 0) * 8 + b) * 256];
    const float* p1 = &prob_ws[((q0 + 1) * 8 + b) * 256];
    const float* p2 = &prob_ws[((q0 + 2) * 8 + b) * 256];
    const float* p3 = &prob_ws[((q0 + 3) * 8 + b) * 256];

    for (int k = 0; k < 256; k += 4) {
        const float4 a = *(const float4*)&p0[k];
        const float4 bq = *(const float4*)&p1[k];
        const float4 c = *(const float4*)&p2[k];
        const float4 d = *(const float4*)&p3[k];
        const float ck0 = ckey[((k + 0) * 8 + b) * 512 + h];
        const float ck1 = ckey[((k + 1) * 8 + b) * 512 + h];
        const float ck2 = ckey[((k + 2) * 8 + b) * 512 + h];
        const float ck3 = ckey[((k + 3) * 8 + b) * 512 + h];
        acc0 = fmaf(a.x, ck0, acc0); acc0 = fmaf(a.y, ck1, acc0);
        acc0 = fmaf(a.z, ck2, acc0); acc0 = fmaf(a.w, ck3, acc0);
        acc1 = fmaf(bq.x, ck0, acc1); acc1 = fmaf(bq.y, ck1, acc1);
        acc1 = fmaf(bq.z, ck2, acc1); acc1 = fmaf(bq.w, ck3, acc1);
        acc2 = fmaf(c.x, ck0, acc2); acc2 = fmaf(c.y, ck1, acc2);
        acc2 = fmaf(c.z, ck2, acc2); acc2 = fmaf(c.w, ck3, acc2);
        acc3 = fmaf(d.x, ck0, acc3); acc3 = fmaf(d.y, ck1, acc3);
        acc3 = fmaf(d.z, ck2, acc3); acc3 = fmaf(d.w, ck3, acc3);
    }
    out[((q0 + 0) * 8 + b) * 512 + h] = acc0;
    out[((q0 + 1) * 8 + b) * 512 + h] = acc1;
    out[((q0 + 2) * 8 + b) * 512 + h] = acc2;
    out[((q0 + 3) * 8 + b) * 512 + h] = acc3;
}

// ---------------------------------------------------------------------------
extern "C" void kernel_launch(void* const* d_in, const int* in_sizes, int n_in,
                              void* d_out, int out_size, void* d_ws, size_t ws_size,
                              hipStream_t stream)
{
    const float* qry  = (const float*)d_in[0];   // [128][8][512]
    const float* ckey = (const float*)d_in[1];   // [256][8][512]
    const int*   mask = (const int*)d_in[2];     // [256][8] (bool -> int32)
    const float* W1   = (const float*)d_in[3];   // [1024][512]
    const float* b1   = (const float*)d_in[4];   // [512]
    const float* W2   = (const float*)d_in[5];   // [512]
    const float* b2   = (const float*)d_in[6];   // [1]

    float* out_ant  = (float*)d_out;                         // [128][8][512]
    float* out_prob = (float*)d_out + T_Q * BB * NHID;       // [256][128][8]

    float* ws      = (float*)d_ws;
    float* ws_kp   = ws;                         // [2048][512]  4 MB
    float* ws_qp   = ws + 1048576;               // [1024][512]  2 MB
    float* ws_sc   = ws + 1572864;               // [1024][256]  1 MB
    float* ws_prob = ws + 1835008;               // [1024][256]  1 MB

    proj_kernel<<<dim3(48, 8, 1), 256, 0, stream>>>(qry, ckey, W1, b1, ws_kp, ws_qp);
    score_kernel<<<dim3(32, 8, 2), 256, 0, stream>>>(ws_kp, ws_qp, W2, b2, mask, ws_sc);
    softmax_kernel<<<dim3(256, 1, 1), 256, 0, stream>>>(ws_sc, out_prob, ws_prob);
    antvec_kernel<<<dim3(32, 8, 2), 256, 0, stream>>>(ckey, ws_prob, out_ant);
}

// Round 2
// 161.255 us; speedup vs baseline: 1.2165x; 1.2165x over previous
//
#include <hip/hip_runtime.h>
#include <math.h>

// Problem constants
#define NHID 512
#define T_K  256
#define T_Q  128
#define BB   8

// 2*log2(e): tanh(x) = 1 - 2/(exp2(C*x)+1)
constexpr float C2L2E = 2.8853900817779268f;
constexpr float L2E   = 1.4426950408889634f;

__device__ __forceinline__ float fexp2(float x) { return __builtin_amdgcn_exp2f(x); }
__device__ __forceinline__ float frcp(float x)  { return __builtin_amdgcn_rcpf(x); }

// ---------------------------------------------------------------------------
// Kernel 1: fused projection GEMM (unchanged from R1).
// Rows 0..2047  : c_key rows  (k*8+b)  -> kp' = (ck @ W1[:512] + b1) * C2L2E
// Rows 2048..3071: query rows (q*8+b)  -> qp' = (q  @ W1[512:])      * C2L2E
// ---------------------------------------------------------------------------
__global__ __launch_bounds__(256) void proj_kernel(
    const float* __restrict__ qry, const float* __restrict__ ckey,
    const float* __restrict__ W1, const float* __restrict__ b1,
    float* __restrict__ kp, float* __restrict__ qp)
{
    const int row0 = blockIdx.x * 64;   // 48 tiles
    const int col0 = blockIdx.y * 64;   // 8 tiles
    const bool isK = row0 < 2048;
    const float* __restrict__ A  = isK ? ckey : qry;
    const int arow0              = isK ? row0 : row0 - 2048;
    const float* __restrict__ Bm = isK ? W1 : (W1 + 512 * 512);

    __shared__ float As[16][64];
    __shared__ float Bs[16][64];

    const int t  = threadIdx.x;
    const int tx = t & 15, ty = t >> 4;

    float acc[4][4] = {};

    for (int k0 = 0; k0 < 512; k0 += 16) {
        {
            const int r  = t >> 2;
            const int c4 = (t & 3) * 4;
            const float4 av = *(const float4*)&A[(arow0 + r) * 512 + k0 + c4];
            As[c4 + 0][r] = av.x; As[c4 + 1][r] = av.y;
            As[c4 + 2][r] = av.z; As[c4 + 3][r] = av.w;
            const int kr  = t >> 4;
            const int c4b = (t & 15) * 4;
            *(float4*)&Bs[kr][c4b] = *(const float4*)&Bm[(k0 + kr) * 512 + col0 + c4b];
        }
        __syncthreads();
        #pragma unroll
        for (int kk = 0; kk < 16; ++kk) {
            const float4 a4 = *(const float4*)&As[kk][ty * 4];
            const float4 b4 = *(const float4*)&Bs[kk][tx * 4];
            const float a[4]  = {a4.x, a4.y, a4.z, a4.w};
            const float bb[4] = {b4.x, b4.y, b4.z, b4.w};
            #pragma unroll
            for (int i = 0; i < 4; ++i)
                #pragma unroll
                for (int j = 0; j < 4; ++j)
                    acc[i][j] = fmaf(a[i], bb[j], acc[i][j]);
        }
        __syncthreads();
    }

    const int col = col0 + tx * 4;
    const float4 bv = *(const float4*)&b1[col];
    #pragma unroll
    for (int i = 0; i < 4; ++i) {
        const int row = row0 + ty * 4 + i;
        float4 o;
        if (isK) {
            o.x = (acc[i][0] + bv.x) * C2L2E;
            o.y = (acc[i][1] + bv.y) * C2L2E;
            o.z = (acc[i][2] + bv.z) * C2L2E;
            o.w = (acc[i][3] + bv.w) * C2L2E;
            *(float4*)&kp[row * 512 + col] = o;
        } else {
            o.x = acc[i][0] * C2L2E; o.y = acc[i][1] * C2L2E;
            o.z = acc[i][2] * C2L2E; o.w = acc[i][3] * C2L2E;
            *(float4*)&qp[(row - 2048) * 512 + col] = o;
        }
    }
}

// ---------------------------------------------------------------------------
// Kernel 2 (REWRITTEN): lane-per-k score kernel. No cross-lane ops in the
// hot loop. Grid (4 k-tiles, 32 q-groups, 8 b), 256 thr = 4 waves.
// Wave w handles q = blockIdx.y*4+w (wave-uniform -> qp/W2 via s_load).
// Lane l owns k = blockIdx.x*64 + l and accumulates
//   racc = sum_h W2[h] / (exp2(kp'[k,b,h] + qp'[q,b,h]) + 1)
// kp is staged transposed into LDS kps[h][k] (stride 65, conflict-free
// reads), 16 h per chunk, register-prefetched one chunk ahead.
// score = (sumW2 + b2) - 2*racc; mask -> -inf; write [q*8+b][k].
// ---------------------------------------------------------------------------
__global__ __launch_bounds__(256) void score_kernel(
    const float* __restrict__ kp, const float* __restrict__ qp,
    const float* __restrict__ W2, const float* __restrict__ b2,
    const int* __restrict__ mask, float* __restrict__ score)
{
    const int t    = threadIdx.x;
    const int lane = t & 63;
    const int wave = __builtin_amdgcn_readfirstlane(t >> 6);
    const int k0   = blockIdx.x * 64;
    const int q    = blockIdx.y * 4 + wave;
    const int b    = blockIdx.z;

    __shared__ float kps[16 * 65];

    const float* __restrict__ qrow = qp + (size_t)(q * 8 + b) * 512;

    // staging map: thread t -> k-offset sk = t>>2, h-quad sh = (t&3)*4
    const int sk = t >> 2;
    const int sh = (t & 3) * 4;
    const float* __restrict__ krow = kp + (size_t)((k0 + sk) * 8 + b) * 512 + sh;

    // base = sum(W2) + b2 (once, outside hot loop)
    const float4 wA = *(const float4*)&W2[lane * 4];
    const float4 wB = *(const float4*)&W2[256 + lane * 4];
    float s2 = wA.x + wA.y + wA.z + wA.w + wB.x + wB.y + wB.z + wB.w;
    #pragma unroll
    for (int m = 32; m; m >>= 1) s2 += __shfl_xor(s2, m, 64);
    const float base = s2 + b2[0];

    float racc = 0.0f;
    float4 stage = *(const float4*)krow;          // chunk 0 prefetch

    for (int hc = 0; hc < 512; hc += 16) {
        __syncthreads();                          // prev chunk reads done
        kps[(sh + 0) * 65 + sk] = stage.x;
        kps[(sh + 1) * 65 + sk] = stage.y;
        kps[(sh + 2) * 65 + sk] = stage.z;
        kps[(sh + 3) * 65 + sk] = stage.w;
        __syncthreads();
        if (hc + 16 < 512)
            stage = *(const float4*)(krow + hc + 16);  // prefetch next chunk
        #pragma unroll
        for (int h = 0; h < 16; ++h) {
            const float kh = kps[h * 65 + lane];       // ds_read, conflict-free
            const float x  = kh + qrow[hc + h];        // + wave-uniform (sgpr)
            racc = fmaf(W2[hc + h], frcp(fexp2(x) + 1.0f), racc);
        }
    }

    const int k = k0 + lane;
    float sc = base - 2.0f * racc;
    if (mask[k * 8 + b]) sc = -INFINITY;
    score[(size_t)(q * 8 + b) * 256 + k] = sc;
}

// ---------------------------------------------------------------------------
// Kernel 3: softmax over k (256) per (q,b). One wave per (q,b). Unchanged.
// ---------------------------------------------------------------------------
__global__ __launch_bounds__(256) void softmax_kernel(
    const float* __restrict__ score, float* __restrict__ prob_out,
    float* __restrict__ prob_ws)
{
    const int t = threadIdx.x;
    const int wave = t >> 6, lane = t & 63;
    const int qb = blockIdx.x * 4 + wave;      // = q*8+b

    float4 s4 = *(const float4*)&score[qb * 256 + lane * 4];
    float m = fmaxf(fmaxf(s4.x, s4.y), fmaxf(s4.z, s4.w));
    #pragma unroll
    for (int d = 32; d; d >>= 1) m = fmaxf(m, __shfl_xor(m, d, 64));

    float4 p;
    p.x = fexp2((s4.x - m) * L2E);
    p.y = fexp2((s4.y - m) * L2E);
    p.z = fexp2((s4.z - m) * L2E);
    p.w = fexp2((s4.w - m) * L2E);
    float sum = p.x + p.y + p.z + p.w;
    #pragma unroll
    for (int d = 32; d; d >>= 1) sum += __shfl_xor(sum, d, 64);
    const float inv = frcp(sum);
    p.x *= inv; p.y *= inv; p.z *= inv; p.w *= inv;

    *(float4*)&prob_ws[qb * 256 + lane * 4] = p;

    const int q = qb >> 3, b = qb & 7;
    const int kbase = lane * 4;
    prob_out[(kbase + 0) * (T_Q * BB) + q * 8 + b] = p.x;
    prob_out[(kbase + 1) * (T_Q * BB) + q * 8 + b] = p.y;
    prob_out[(kbase + 2) * (T_Q * BB) + q * 8 + b] = p.z;
    prob_out[(kbase + 3) * (T_Q * BB) + q * 8 + b] = p.w;
}

// ---------------------------------------------------------------------------
// Kernel 4: ant_vec[q,b,h] = sum_k prob[k,q,b] * c_key[k,b,h]. Unchanged.
// ---------------------------------------------------------------------------
__global__ __launch_bounds__(256) void antvec_kernel(
    const float* __restrict__ ckey, const float* __restrict__ prob_ws,
    float* __restrict__ out)
{
    const int q0 = blockIdx.x * 4;             // 32 tiles
    const int b  = blockIdx.y;                 // 8
    const int h  = blockIdx.z * 256 + threadIdx.x;  // 2 halves

    float acc0 = 0.f, acc1 = 0.f, acc2 = 0.f, acc3 = 0.f;
    const float* p0 = &prob_ws[((q0 + 0) * 8 + b) * 256];
    const float* p1 = &prob_ws[((q0 + 1) * 8 + b) * 256];
    const float* p2 = &prob_ws[((q0 + 2) * 8 + b) * 256];
    const float* p3 = &prob_ws[((q0 + 3) * 8 + b) * 256];

    for (int k = 0; k < 256; k += 4) {
        const float4 a = *(const float4*)&p0[k];
        const float4 bq = *(const float4*)&p1[k];
        const float4 c = *(const float4*)&p2[k];
        const float4 d = *(const float4*)&p3[k];
        const float ck0 = ckey[((k + 0) * 8 + b) * 512 + h];
        const float ck1 = ckey[((k + 1) * 8 + b) * 512 + h];
        const float ck2 = ckey[((k + 2) * 8 + b) * 512 + h];
        const float ck3 = ckey[((k + 3) * 8 + b) * 512 + h];
        acc0 = fmaf(a.x, ck0, acc0); acc0 = fmaf(a.y, ck1, acc0);
        acc0 = fmaf(a.z, ck2, acc0); acc0 = fmaf(a.w, ck3, acc0);
        acc1 = fmaf(bq.x, ck0, acc1); acc1 = fmaf(bq.y, ck1, acc1);
        acc1 = fmaf(bq.z, ck2, acc1); acc1 = fmaf(bq.w, ck3, acc1);
        acc2 = fmaf(c.x, ck0, acc2); acc2 = fmaf(c.y, ck1, acc2);
        acc2 = fmaf(c.z, ck2, acc2); acc2 = fmaf(c.w, ck3, acc2);
        acc3 = fmaf(d.x, ck0, acc3); acc3 = fmaf(d.y, ck1, acc3);
        acc3 = fmaf(d.z, ck2, acc3); acc3 = fmaf(d.w, ck3, acc3);
    }
    out[((q0 + 0) * 8 + b) * 512 + h] = acc0;
    out[((q0 + 1) * 8 + b) * 512 + h] = acc1;
    out[((q0 + 2) * 8 + b) * 512 + h] = acc2;
    out[((q0 + 3) * 8 + b) * 512 + h] = acc3;
}

// ---------------------------------------------------------------------------
extern "C" void kernel_launch(void* const* d_in, const int* in_sizes, int n_in,
                              void* d_out, int out_size, void* d_ws, size_t ws_size,
                              hipStream_t stream)
{
    const float* qry  = (const float*)d_in[0];   // [128][8][512]
    const float* ckey = (const float*)d_in[1];   // [256][8][512]
    const int*   mask = (const int*)d_in[2];     // [256][8] (bool -> int32)
    const float* W1   = (const float*)d_in[3];   // [1024][512]
    const float* b1   = (const float*)d_in[4];   // [512]
    const float* W2   = (const float*)d_in[5];   // [512]
    const float* b2   = (const float*)d_in[6];   // [1]

    float* out_ant  = (float*)d_out;                         // [128][8][512]
    float* out_prob = (float*)d_out + T_Q * BB * NHID;       // [256][128][8]

    float* ws      = (float*)d_ws;
    float* ws_kp   = ws;                         // [2048][512]  4 MB
    float* ws_qp   = ws + 1048576;               // [1024][512]  2 MB
    float* ws_sc   = ws + 1572864;               // [1024][256]  1 MB
    float* ws_prob = ws + 1835008;               // [1024][256]  1 MB

    proj_kernel<<<dim3(48, 8, 1), 256, 0, stream>>>(qry, ckey, W1, b1, ws_kp, ws_qp);
    score_kernel<<<dim3(4, 32, 8), 256, 0, stream>>>(ws_kp, ws_qp, W2, b2, mask, ws_sc);
    softmax_kernel<<<dim3(256, 1, 1), 256, 0, stream>>>(ws_sc, out_prob, ws_prob);
    antvec_kernel<<<dim3(32, 8, 2), 256, 0, stream>>>(ckey, ws_prob, out_ant);
}

// Round 3
// 144.057 us; speedup vs baseline: 1.3618x; 1.1194x over previous
//
#include <hip/hip_runtime.h>
#include <math.h>

#define NHID 512
#define T_K  256
#define T_Q  128
#define BB   8

// 2*log2(e): tanh(x) = 1 - 2/(exp2(C*x)+1)
constexpr float C2L2E = 2.8853900817779268f;
constexpr float L2E   = 1.4426950408889634f;

__device__ __forceinline__ float fexp2(float x) { return __builtin_amdgcn_exp2f(x); }
__device__ __forceinline__ float frcp(float x)  { return __builtin_amdgcn_rcpf(x); }

typedef __attribute__((ext_vector_type(8))) short bf16x8;
typedef __attribute__((ext_vector_type(4))) float f32x4;

__device__ __forceinline__ unsigned short f2bf(float x) {
    unsigned u = __builtin_bit_cast(unsigned, x);
    unsigned r = (u + 0x7FFFu + ((u >> 16) & 1u)) >> 16;
    return (unsigned short)r;
}
__device__ __forceinline__ float bf2f(unsigned short h) {
    unsigned u = ((unsigned)h) << 16;
    return __builtin_bit_cast(float, u);
}

// ---------------------------------------------------------------------------
// Kernel 0: convert/split. Blocks 0..1535: A = [ckey(2048 rows); qry(1024)]
// fp32 -> A_hi/A_lo bf16 [3072][512]. Blocks 1536..1663: W1 [1024][512]
// -> BT_hi/BT_lo [1024][512] with BT[half*512 + n][k] = W1[half*512 + k][n].
// ---------------------------------------------------------------------------
__global__ __launch_bounds__(256) void convert_kernel(
    const float* __restrict__ qry, const float* __restrict__ ckey,
    const float* __restrict__ W1,
    unsigned short* __restrict__ a_hi, unsigned short* __restrict__ a_lo,
    unsigned short* __restrict__ bt_hi, unsigned short* __restrict__ bt_lo)
{
    const int bid = blockIdx.x;
    const int t   = threadIdx.x;
    if (bid < 1536) {
        const size_t idx = (size_t)bid * 1024 + t * 4;
        const float* src = (idx < (size_t)2048 * 512) ? (ckey + idx)
                                                      : (qry + (idx - (size_t)2048 * 512));
        const float4 v = *(const float4*)src;
        ushort4 h, l;
        h.x = f2bf(v.x); l.x = f2bf(v.x - bf2f(h.x));
        h.y = f2bf(v.y); l.y = f2bf(v.y - bf2f(h.y));
        h.z = f2bf(v.z); l.z = f2bf(v.z - bf2f(h.z));
        h.w = f2bf(v.w); l.w = f2bf(v.w - bf2f(h.w));
        *(ushort4*)&a_hi[idx] = h;
        *(ushort4*)&a_lo[idx] = l;
    } else {
        const int tb = bid - 1536;   // 0..127
        const int kt = tb & 15;      // 16 k'-tiles of 64 (k' in [0,1024))
        const int nt = tb >> 4;      // 8 n-tiles of 64
        __shared__ float tile[64][65];
        const int r  = t >> 2;         // 0..63
        const int c0 = (t & 3) * 16;   // 0,16,32,48
        const float* src = W1 + (size_t)(kt * 64 + r) * 512 + nt * 64 + c0;
        #pragma unroll
        for (int j = 0; j < 4; ++j) {
            const float4 v = *(const float4*)&src[j * 4];
            tile[r][c0 + j * 4 + 0] = v.x; tile[r][c0 + j * 4 + 1] = v.y;
            tile[r][c0 + j * 4 + 2] = v.z; tile[r][c0 + j * 4 + 3] = v.w;
        }
        __syncthreads();
        // write row n = nt*64 + r, k-cols (kt&7)*64 + c0 + j  (half = kt>>3)
        const size_t dst = (size_t)((kt >> 3) * 512 + nt * 64 + r) * 512
                         + (size_t)((kt & 7) * 64 + c0);
        #pragma unroll
        for (int j4 = 0; j4 < 4; ++j4) {
            ushort4 h, l;
            #pragma unroll
            for (int e = 0; e < 4; ++e) {
                const float x = tile[c0 + j4 * 4 + e][r];
                const unsigned short hb = f2bf(x);
                const unsigned short lb = f2bf(x - bf2f(hb));
                ((unsigned short*)&h)[e] = hb;
                ((unsigned short*)&l)[e] = lb;
            }
            *(ushort4*)&bt_hi[dst + j4 * 4] = h;
            *(ushort4*)&bt_lo[dst + j4 * 4] = l;
        }
    }
}

// ---------------------------------------------------------------------------
// Kernel 1: proj GEMM via split-bf16 MFMA (16x16x32), D = ah*bh + ah*bl + al*bh.
// 64x64 tile, 4 waves each own a 32x32 quadrant (2x2 MFMA tiles).
// LDS: A/B hi+lo 64x64 bf16 each, XOR-swizzled k-chunks for conflict-free b128.
// Epilogue: kp = (acc + b1)*C2L2E (rows<2048), qp = acc*C2L2E.
// ---------------------------------------------------------------------------
__global__ __launch_bounds__(256) void proj_kernel(
    const unsigned short* __restrict__ a_hi, const unsigned short* __restrict__ a_lo,
    const unsigned short* __restrict__ bt_hi, const unsigned short* __restrict__ bt_lo,
    const float* __restrict__ b1,
    float* __restrict__ kp, float* __restrict__ qp)
{
    const int row0 = blockIdx.x * 64;   // 48
    const int col0 = blockIdx.y * 64;   // 8
    const bool isK = row0 < 2048;
    const int bhalf = isK ? 0 : 512;

    __shared__ __align__(16) unsigned short As_h[64 * 64];
    __shared__ __align__(16) unsigned short As_l[64 * 64];
    __shared__ __align__(16) unsigned short Bs_h[64 * 64];
    __shared__ __align__(16) unsigned short Bs_l[64 * 64];

    const int t    = threadIdx.x;
    const int wave = t >> 6;
    const int lane = t & 63;
    const int wm = (wave & 1) * 32;
    const int wn = (wave >> 1) * 32;

    f32x4 acc[2][2] = {};

    // staging: row sr = t>>2 (0..63), 16 bf16 at col sc = (t&3)*16
    const int sr = t >> 2;
    const int sc = (t & 3) * 16;
    const unsigned short* gAh = a_hi + (size_t)(row0 + sr) * 512 + sc;
    const unsigned short* gAl = a_lo + (size_t)(row0 + sr) * 512 + sc;
    const unsigned short* gBh = bt_hi + (size_t)(bhalf + col0 + sr) * 512 + sc;
    const unsigned short* gBl = bt_lo + (size_t)(bhalf + col0 + sr) * 512 + sc;
    const int c0c = sc >> 3;                       // chunk index (8-bf16 units)
    const int sw0 = ((c0c + 0) ^ (sr & 7)) * 8;
    const int sw1 = ((c0c + 1) ^ (sr & 7)) * 8;

    const int quad = lane >> 4, fr = lane & 15;

    for (int k0 = 0; k0 < 512; k0 += 64) {
        __syncthreads();
        {
            uint4 v0, v1;
            v0 = *(const uint4*)&gAh[k0];     v1 = *(const uint4*)&gAh[k0 + 8];
            *(uint4*)&As_h[sr * 64 + sw0] = v0; *(uint4*)&As_h[sr * 64 + sw1] = v1;
            v0 = *(const uint4*)&gAl[k0];     v1 = *(const uint4*)&gAl[k0 + 8];
            *(uint4*)&As_l[sr * 64 + sw0] = v0; *(uint4*)&As_l[sr * 64 + sw1] = v1;
            v0 = *(const uint4*)&gBh[k0];     v1 = *(const uint4*)&gBh[k0 + 8];
            *(uint4*)&Bs_h[sr * 64 + sw0] = v0; *(uint4*)&Bs_h[sr * 64 + sw1] = v1;
            v0 = *(const uint4*)&gBl[k0];     v1 = *(const uint4*)&gBl[k0 + 8];
            *(uint4*)&Bs_l[sr * 64 + sw0] = v0; *(uint4*)&Bs_l[sr * 64 + sw1] = v1;
        }
        __syncthreads();
        #pragma unroll
        for (int ks = 0; ks < 2; ++ks) {
            const int cchunk = ks * 4 + quad;
            bf16x8 afh[2], afl[2], bfh[2], bfl[2];
            #pragma unroll
            for (int mt = 0; mt < 2; ++mt) {
                const int m = wm + mt * 16 + fr;
                afh[mt] = *(const bf16x8*)&As_h[m * 64 + ((cchunk ^ (m & 7)) * 8)];
                afl[mt] = *(const bf16x8*)&As_l[m * 64 + ((cchunk ^ (m & 7)) * 8)];
            }
            #pragma unroll
            for (int nt = 0; nt < 2; ++nt) {
                const int n = wn + nt * 16 + fr;
                bfh[nt] = *(const bf16x8*)&Bs_h[n * 64 + ((cchunk ^ (n & 7)) * 8)];
                bfl[nt] = *(const bf16x8*)&Bs_l[n * 64 + ((cchunk ^ (n & 7)) * 8)];
            }
            #pragma unroll
            for (int mt = 0; mt < 2; ++mt)
                #pragma unroll
                for (int nt = 0; nt < 2; ++nt) {
                    acc[mt][nt] = __builtin_amdgcn_mfma_f32_16x16x32_bf16(afh[mt], bfh[nt], acc[mt][nt], 0, 0, 0);
                    acc[mt][nt] = __builtin_amdgcn_mfma_f32_16x16x32_bf16(afh[mt], bfl[nt], acc[mt][nt], 0, 0, 0);
                    acc[mt][nt] = __builtin_amdgcn_mfma_f32_16x16x32_bf16(afl[mt], bfh[nt], acc[mt][nt], 0, 0, 0);
                }
        }
    }

    // epilogue: D[row=quad*4+i][col=fr] per 16x16 tile (verified C/D layout)
    #pragma unroll
    for (int nt = 0; nt < 2; ++nt) {
        const int colg = col0 + wn + nt * 16 + fr;
        const float b1v = b1[colg];
        #pragma unroll
        for (int mt = 0; mt < 2; ++mt) {
            #pragma unroll
            for (int i = 0; i < 4; ++i) {
                const int rowg = row0 + wm + mt * 16 + quad * 4 + i;
                const float v = acc[mt][nt][i];
                if (isK) kp[(size_t)rowg * 512 + colg] = (v + b1v) * C2L2E;
                else     qp[(size_t)(rowg - 2048) * 512 + colg] = v * C2L2E;
            }
        }
    }
}

// ---------------------------------------------------------------------------
// Kernel 2: score. Block = (32 k) x (16 q) x (1 b); 4 waves, wave -> 4 q.
// Lane: k = lane>>1, h-parity p = lane&1 (pairs (4s+2p, 4s+2p+1)).
// Paired-rcp: w0/(t0+1)+w1/(t1+1) = fma(w0,t1,fma(w1,t0,ws)) * rcp(fma(t0,t1+1,t1+1))
// -> 1.5 transcendentals per element. 64-h double-buffered LDS chunks.
// ---------------------------------------------------------------------------
__global__ __launch_bounds__(256) void score_kernel(
    const float* __restrict__ kp, const float* __restrict__ qp,
    const float* __restrict__ W2, const float* __restrict__ b2,
    const int* __restrict__ mask, float* __restrict__ score)
{
    const int t    = threadIdx.x;
    const int wave = __builtin_amdgcn_readfirstlane(t >> 6);
    const int lane = t & 63;
    const int kk = lane >> 1;
    const int p  = lane & 1;
    const int k0 = blockIdx.x * 32;
    const int q0b = blockIdx.y * 16;
    const int b  = blockIdx.z;

    __shared__ float kb[2][32][66];
    __shared__ float qb[2][16][66];

    // base = sum(W2) + b2
    const float4 wA = *(const float4*)&W2[lane * 4];
    const float4 wB = *(const float4*)&W2[256 + lane * 4];
    float s2 = wA.x + wA.y + wA.z + wA.w + wB.x + wB.y + wB.z + wB.w;
    #pragma unroll
    for (int m = 32; m; m >>= 1) s2 += __shfl_xor(s2, m, 64);
    const float base = s2 + b2[0];

    // staging maps
    const int srk = t >> 3;            // 0..31
    const int sck = (t & 7) * 8;       // 0..56
    const float* kp_src = kp + ((size_t)(k0 + srk) * 8 + b) * 512 + sck;
    const int srq = t >> 4;            // 0..15
    const int scq = (t & 15) * 4;      // 0..60
    const float* qp_src = qp + ((size_t)(q0b + srq) * 8 + b) * 512 + scq;

    float4 pk0 = *(const float4*)&kp_src[0];
    float4 pk1 = *(const float4*)&kp_src[4];
    float4 pq0 = *(const float4*)&qp_src[0];

    // write chunk 0 into buf 0
    *(float2*)&kb[0][srk][sck + 0] = {pk0.x, pk0.y};
    *(float2*)&kb[0][srk][sck + 2] = {pk0.z, pk0.w};
    *(float2*)&kb[0][srk][sck + 4] = {pk1.x, pk1.y};
    *(float2*)&kb[0][srk][sck + 6] = {pk1.z, pk1.w};
    *(float2*)&qb[0][srq][scq + 0] = {pq0.x, pq0.y};
    *(float2*)&qb[0][srq][scq + 2] = {pq0.z, pq0.w};
    __syncthreads();

    float racc[4] = {0.f, 0.f, 0.f, 0.f};

    for (int chunk = 0; chunk < 8; ++chunk) {
        const int buf = chunk & 1;
        const int hc = chunk * 64;
        if (chunk < 7) {
            pk0 = *(const float4*)&kp_src[hc + 64];
            pk1 = *(const float4*)&kp_src[hc + 68];
            pq0 = *(const float4*)&qp_src[hc + 64];
        }
        #pragma unroll
        for (int s = 0; s < 16; ++s) {
            const float2 k01 = *(const float2*)&kb[buf][kk][4 * s + 2 * p];
            const float2 w01 = *(const float2*)&W2[hc + 4 * s + 2 * p];
            const float ws = w01.x + w01.y;
            #pragma unroll
            for (int qi = 0; qi < 4; ++qi) {
                const float2 q01 = *(const float2*)&qb[buf][wave * 4 + qi][4 * s + 2 * p];
                const float x0 = k01.x + q01.x;
                const float x1 = k01.y + q01.y;
                const float t0 = fexp2(x0);
                const float t1 = fexp2(x1);
                const float tb1 = t1 + 1.0f;
                const float den = fmaf(t0, tb1, tb1);
                const float num = fmaf(w01.x, t1, fmaf(w01.y, t0, ws));
                racc[qi] = fmaf(num, frcp(den), racc[qi]);
            }
        }
        __syncthreads();
        if (chunk < 7) {
            const int nb = buf ^ 1;
            *(float2*)&kb[nb][srk][sck + 0] = {pk0.x, pk0.y};
            *(float2*)&kb[nb][srk][sck + 2] = {pk0.z, pk0.w};
            *(float2*)&kb[nb][srk][sck + 4] = {pk1.x, pk1.y};
            *(float2*)&kb[nb][srk][sck + 6] = {pk1.z, pk1.w};
            *(float2*)&qb[nb][srq][scq + 0] = {pq0.x, pq0.y};
            *(float2*)&qb[nb][srq][scq + 2] = {pq0.z, pq0.w};
        }
        __syncthreads();
    }

    const int kglob = k0 + kk;
    const int msk = mask[kglob * 8 + b];
    #pragma unroll
    for (int qi = 0; qi < 4; ++qi) {
        float r = racc[qi] + __shfl_xor(racc[qi], 1, 64);
        float sc = base - 2.0f * r;
        if (msk) sc = -INFINITY;
        if (p == 0)
            score[((size_t)(q0b + wave * 4 + qi) * 8 + b) * 256 + kglob] = sc;
    }
}

// ---------------------------------------------------------------------------
// Kernel 3: softmax over k (256) per (q,b). One wave per (q,b).
// ---------------------------------------------------------------------------
__global__ __launch_bounds__(256) void softmax_kernel(
    const float* __restrict__ score, float* __restrict__ prob_out,
    float* __restrict__ prob_ws)
{
    const int t = threadIdx.x;
    const int wave = t >> 6, lane = t & 63;
    const int qb = blockIdx.x * 4 + wave;

    float4 s4 = *(const float4*)&score[qb * 256 + lane * 4];
    float m = fmaxf(fmaxf(s4.x, s4.y), fmaxf(s4.z, s4.w));
    #pragma unroll
    for (int d = 32; d; d >>= 1) m = fmaxf(m, __shfl_xor(m, d, 64));

    float4 pv;
    pv.x = fexp2((s4.x - m) * L2E);
    pv.y = fexp2((s4.y - m) * L2E);
    pv.z = fexp2((s4.z - m) * L2E);
    pv.w = fexp2((s4.w - m) * L2E);
    float sum = pv.x + pv.y + pv.z + pv.w;
    #pragma unroll
    for (int d = 32; d; d >>= 1) sum += __shfl_xor(sum, d, 64);
    const float inv = frcp(sum);
    pv.x *= inv; pv.y *= inv; pv.z *= inv; pv.w *= inv;

    *(float4*)&prob_ws[qb * 256 + lane * 4] = pv;

    const int q = qb >> 3, b = qb & 7;
    const int kbase = lane * 4;
    prob_out[(kbase + 0) * (T_Q * BB) + q * 8 + b] = pv.x;
    prob_out[(kbase + 1) * (T_Q * BB) + q * 8 + b] = pv.y;
    prob_out[(kbase + 2) * (T_Q * BB) + q * 8 + b] = pv.z;
    prob_out[(kbase + 3) * (T_Q * BB) + q * 8 + b] = pv.w;
}

// ---------------------------------------------------------------------------
// Kernel 4: ant_vec[q,b,h] = sum_k prob[k,q,b] * c_key[k,b,h].
// Block (4 q, 1 b), 256 thr: thread owns 2 h (float2), loops all 256 k.
// prob reads are wave-uniform -> s_load.
// ---------------------------------------------------------------------------
__global__ __launch_bounds__(256) void antvec_kernel(
    const float* __restrict__ ckey, const float* __restrict__ prob_ws,
    float* __restrict__ out)
{
    const int q0 = blockIdx.x * 4;
    const int b  = blockIdx.y;
    const int h2 = threadIdx.x * 2;

    float2 acc[4] = {{0.f,0.f},{0.f,0.f},{0.f,0.f},{0.f,0.f}};
    #pragma unroll 4
    for (int k = 0; k < 256; ++k) {
        const float2 ck = *(const float2*)&ckey[((size_t)k * 8 + b) * 512 + h2];
        #pragma unroll
        for (int qi = 0; qi < 4; ++qi) {
            const float pq = prob_ws[((size_t)(q0 + qi) * 8 + b) * 256 + k];
            acc[qi].x = fmaf(pq, ck.x, acc[qi].x);
            acc[qi].y = fmaf(pq, ck.y, acc[qi].y);
        }
    }
    #pragma unroll
    for (int qi = 0; qi < 4; ++qi)
        *(float2*)&out[((size_t)(q0 + qi) * 8 + b) * 512 + h2] = acc[qi];
}

// ---------------------------------------------------------------------------
extern "C" void kernel_launch(void* const* d_in, const int* in_sizes, int n_in,
                              void* d_out, int out_size, void* d_ws, size_t ws_size,
                              hipStream_t stream)
{
    const float* qry  = (const float*)d_in[0];   // [128][8][512]
    const float* ckey = (const float*)d_in[1];   // [256][8][512]
    const int*   mask = (const int*)d_in[2];     // [256][8]
    const float* W1   = (const float*)d_in[3];   // [1024][512]
    const float* b1   = (const float*)d_in[4];   // [512]
    const float* W2   = (const float*)d_in[5];   // [512]
    const float* b2   = (const float*)d_in[6];   // [1]

    float* out_ant  = (float*)d_out;                      // [128][8][512]
    float* out_prob = (float*)d_out + T_Q * BB * NHID;    // [256][128][8]

    float* ws = (float*)d_ws;
    float* ws_kp = ws;                               // [2048][512] f32, 4MB
    float* ws_qp = ws + 1048576;                     // [1024][512] f32, 2MB
    unsigned short* a_hi  = (unsigned short*)(ws + 1572864); // [3072][512] bf16, 3MB
    unsigned short* a_lo  = (unsigned short*)(ws + 2359296); // 3MB
    unsigned short* bt_hi = (unsigned short*)(ws + 3145728); // [1024][512] bf16, 1MB
    unsigned short* bt_lo = (unsigned short*)(ws + 3407872); // 1MB  (total 14MB)
    // score/prob alias the (dead after proj) a_hi region:
    float* ws_sc   = ws + 1572864;                   // [1024][256] f32, 1MB
    float* ws_prob = ws + 1835008;                   // [1024][256] f32, 1MB

    convert_kernel<<<dim3(1664), 256, 0, stream>>>(qry, ckey, W1, a_hi, a_lo, bt_hi, bt_lo);
    proj_kernel<<<dim3(48, 8), 256, 0, stream>>>(a_hi, a_lo, bt_hi, bt_lo, b1, ws_kp, ws_qp);
    score_kernel<<<dim3(8, 8, 8), 256, 0, stream>>>(ws_kp, ws_qp, W2, b2, mask, ws_sc);
    softmax_kernel<<<dim3(256), 256, 0, stream>>>(ws_sc, out_prob, ws_prob);
    antvec_kernel<<<dim3(32, 8), 256, 0, stream>>>(ckey, ws_prob, out_ant);
}

// Round 4
// 134.768 us; speedup vs baseline: 1.4556x; 1.0689x over previous
//
#include <hip/hip_runtime.h>
#include <math.h>

#define NHID 512
#define T_K  256
#define T_Q  128
#define BB   8

// tanh(x) = 1 - 2/(exp2(C*x)+1), C = 2*log2(e)
constexpr float C2L2E = 2.8853900817779268f;
constexpr float L2E   = 1.4426950408889634f;

__device__ __forceinline__ float fexp2(float x) { return __builtin_amdgcn_exp2f(x); }
__device__ __forceinline__ float frcp(float x)  { return __builtin_amdgcn_rcpf(x); }

typedef __attribute__((ext_vector_type(8))) short bf16x8;
typedef __attribute__((ext_vector_type(4))) float f32x4;

__device__ __forceinline__ unsigned short f2bf(float x) {
    unsigned u = __builtin_bit_cast(unsigned, x);
    unsigned r = (u + 0x7FFFu + ((u >> 16) & 1u)) >> 16;
    return (unsigned short)r;
}
__device__ __forceinline__ float bf2f(unsigned short h) {
    unsigned u = ((unsigned)h) << 16;
    return __builtin_bit_cast(float, u);
}

// ---------------------------------------------------------------------------
// Kernel 0: W1 -> BT_hi/lo (split bf16, transposed: BT[half*512+n][k]=W1[half*512+k][n])
// 128 blocks only.
// ---------------------------------------------------------------------------
__global__ __launch_bounds__(256) void convert_w1_kernel(
    const float* __restrict__ W1,
    unsigned short* __restrict__ bt_hi, unsigned short* __restrict__ bt_lo)
{
    const int tb = blockIdx.x;   // 0..127
    const int kt = tb & 15;      // 16 k'-tiles of 64
    const int nt = tb >> 4;      // 8 n-tiles of 64
    __shared__ float tile[64][65];
    const int t  = threadIdx.x;
    const int r  = t >> 2;
    const int c0 = (t & 3) * 16;
    const float* src = W1 + (size_t)(kt * 64 + r) * 512 + nt * 64 + c0;
    #pragma unroll
    for (int j = 0; j < 4; ++j) {
        const float4 v = *(const float4*)&src[j * 4];
        tile[r][c0 + j * 4 + 0] = v.x; tile[r][c0 + j * 4 + 1] = v.y;
        tile[r][c0 + j * 4 + 2] = v.z; tile[r][c0 + j * 4 + 3] = v.w;
    }
    __syncthreads();
    const size_t dst = (size_t)((kt >> 3) * 512 + nt * 64 + r) * 512
                     + (size_t)((kt & 7) * 64 + c0);
    #pragma unroll
    for (int j4 = 0; j4 < 4; ++j4) {
        ushort4 h, l;
        #pragma unroll
        for (int e = 0; e < 4; ++e) {
            const float x = tile[c0 + j4 * 4 + e][r];
            const unsigned short hb = f2bf(x);
            const unsigned short lb = f2bf(x - bf2f(hb));
            ((unsigned short*)&h)[e] = hb;
            ((unsigned short*)&l)[e] = lb;
        }
        *(ushort4*)&bt_hi[dst + j4 * 4] = h;
        *(ushort4*)&bt_lo[dst + j4 * 4] = l;
    }
}

// ---------------------------------------------------------------------------
// Kernel 1: proj GEMM, split-bf16 MFMA, A converted in-staging from fp32.
// Epilogue applies exp2: ek = exp2((acc+b1)*C), eq = exp2(acc*C).
// ---------------------------------------------------------------------------
__global__ __launch_bounds__(256) void proj_kernel(
    const float* __restrict__ qry, const float* __restrict__ ckey,
    const unsigned short* __restrict__ bt_hi, const unsigned short* __restrict__ bt_lo,
    const float* __restrict__ b1,
    float* __restrict__ ek, float* __restrict__ eq)
{
    const int row0 = blockIdx.x * 64;   // 48
    const int col0 = blockIdx.y * 64;   // 8
    const bool isK = row0 < 2048;
    const int bhalf = isK ? 0 : 512;

    __shared__ __align__(16) unsigned short As_h[64 * 64];
    __shared__ __align__(16) unsigned short As_l[64 * 64];
    __shared__ __align__(16) unsigned short Bs_h[64 * 64];
    __shared__ __align__(16) unsigned short Bs_l[64 * 64];

    const int t    = threadIdx.x;
    const int wave = t >> 6;
    const int lane = t & 63;
    const int wm = (wave & 1) * 32;
    const int wn = (wave >> 1) * 32;

    f32x4 acc[2][2] = {};

    const int sr = t >> 2;
    const int sc = (t & 3) * 16;
    const float* gA = (isK ? ckey + (size_t)(row0 + sr) * 512
                           : qry  + (size_t)(row0 - 2048 + sr) * 512) + sc;
    const unsigned short* gBh = bt_hi + (size_t)(bhalf + col0 + sr) * 512 + sc;
    const unsigned short* gBl = bt_lo + (size_t)(bhalf + col0 + sr) * 512 + sc;
    const int c0c = sc >> 3;
    const int sw0 = ((c0c + 0) ^ (sr & 7)) * 8;
    const int sw1 = ((c0c + 1) ^ (sr & 7)) * 8;

    const int quad = lane >> 4, fr = lane & 15;

    for (int k0 = 0; k0 < 512; k0 += 64) {
        __syncthreads();
        {
            // A: 16 fp32 -> hi/lo bf16 in-register
            float fa[16];
            *(float4*)&fa[0]  = *(const float4*)&gA[k0 + 0];
            *(float4*)&fa[4]  = *(const float4*)&gA[k0 + 4];
            *(float4*)&fa[8]  = *(const float4*)&gA[k0 + 8];
            *(float4*)&fa[12] = *(const float4*)&gA[k0 + 12];
            union { uint4 v; unsigned short s[8]; } h0, l0, h1, l1;
            #pragma unroll
            for (int e = 0; e < 8; ++e) {
                const unsigned short hb = f2bf(fa[e]);
                h0.s[e] = hb; l0.s[e] = f2bf(fa[e] - bf2f(hb));
            }
            #pragma unroll
            for (int e = 0; e < 8; ++e) {
                const unsigned short hb = f2bf(fa[8 + e]);
                h1.s[e] = hb; l1.s[e] = f2bf(fa[8 + e] - bf2f(hb));
            }
            *(uint4*)&As_h[sr * 64 + sw0] = h0.v; *(uint4*)&As_h[sr * 64 + sw1] = h1.v;
            *(uint4*)&As_l[sr * 64 + sw0] = l0.v; *(uint4*)&As_l[sr * 64 + sw1] = l1.v;
            uint4 v0, v1;
            v0 = *(const uint4*)&gBh[k0];     v1 = *(const uint4*)&gBh[k0 + 8];
            *(uint4*)&Bs_h[sr * 64 + sw0] = v0; *(uint4*)&Bs_h[sr * 64 + sw1] = v1;
            v0 = *(const uint4*)&gBl[k0];     v1 = *(const uint4*)&gBl[k0 + 8];
            *(uint4*)&Bs_l[sr * 64 + sw0] = v0; *(uint4*)&Bs_l[sr * 64 + sw1] = v1;
        }
        __syncthreads();
        #pragma unroll
        for (int ks = 0; ks < 2; ++ks) {
            const int cchunk = ks * 4 + quad;
            bf16x8 afh[2], afl[2], bfh[2], bfl[2];
            #pragma unroll
            for (int mt = 0; mt < 2; ++mt) {
                const int m = wm + mt * 16 + fr;
                afh[mt] = *(const bf16x8*)&As_h[m * 64 + ((cchunk ^ (m & 7)) * 8)];
                afl[mt] = *(const bf16x8*)&As_l[m * 64 + ((cchunk ^ (m & 7)) * 8)];
            }
            #pragma unroll
            for (int nt = 0; nt < 2; ++nt) {
                const int n = wn + nt * 16 + fr;
                bfh[nt] = *(const bf16x8*)&Bs_h[n * 64 + ((cchunk ^ (n & 7)) * 8)];
                bfl[nt] = *(const bf16x8*)&Bs_l[n * 64 + ((cchunk ^ (n & 7)) * 8)];
            }
            #pragma unroll
            for (int mt = 0; mt < 2; ++mt)
                #pragma unroll
                for (int nt = 0; nt < 2; ++nt) {
                    acc[mt][nt] = __builtin_amdgcn_mfma_f32_16x16x32_bf16(afh[mt], bfh[nt], acc[mt][nt], 0, 0, 0);
                    acc[mt][nt] = __builtin_amdgcn_mfma_f32_16x16x32_bf16(afh[mt], bfl[nt], acc[mt][nt], 0, 0, 0);
                    acc[mt][nt] = __builtin_amdgcn_mfma_f32_16x16x32_bf16(afl[mt], bfh[nt], acc[mt][nt], 0, 0, 0);
                }
        }
    }

    #pragma unroll
    for (int nt = 0; nt < 2; ++nt) {
        const int colg = col0 + wn + nt * 16 + fr;
        const float b1v = b1[colg];
        #pragma unroll
        for (int mt = 0; mt < 2; ++mt) {
            #pragma unroll
            for (int i = 0; i < 4; ++i) {
                const int rowg = row0 + wm + mt * 16 + quad * 4 + i;
                const float v = acc[mt][nt][i];
                if (isK) ek[(size_t)rowg * 512 + colg] = fexp2((v + b1v) * C2L2E);
                else     eq[(size_t)(rowg - 2048) * 512 + colg] = fexp2(v * C2L2E);
            }
        }
    }
}

// ---------------------------------------------------------------------------
// Kernel 2: score via exp2-factorization. t = ek*eq, 0.5 rcp + 4 VALU / elem.
// Block (32 k, 16 q, 1 b); lane = (k, h-parity); 64-h double-buffered LDS.
// sum-pair: [w0*t1 + w1*t0 + w0+w1] / [t0*t1 + t0 + t1 + 1]
// ---------------------------------------------------------------------------
__global__ __launch_bounds__(256) void score_kernel(
    const float* __restrict__ ek, const float* __restrict__ eq,
    const float* __restrict__ W2, const float* __restrict__ b2,
    const int* __restrict__ mask, float* __restrict__ score)
{
    const int t    = threadIdx.x;
    const int wave = __builtin_amdgcn_readfirstlane(t >> 6);
    const int lane = t & 63;
    const int kk = lane >> 1;
    const int p  = lane & 1;
    const int k0 = blockIdx.x * 32;
    const int q0b = blockIdx.y * 16;
    const int b  = blockIdx.z;

    __shared__ float kb[2][32][66];
    __shared__ float qb[2][16][66];
    __shared__ float w2s[512];

    *(float2*)&w2s[t * 2] = *(const float2*)&W2[t * 2];

    // base = sum(W2) + b2
    const float4 wA = *(const float4*)&W2[lane * 4];
    const float4 wB = *(const float4*)&W2[256 + lane * 4];
    float s2 = wA.x + wA.y + wA.z + wA.w + wB.x + wB.y + wB.z + wB.w;
    #pragma unroll
    for (int m = 32; m; m >>= 1) s2 += __shfl_xor(s2, m, 64);
    const float base = s2 + b2[0];

    const int srk = t >> 3;            // 0..31
    const int sck = (t & 7) * 8;       // 0..56
    const float* ek_src = ek + ((size_t)(k0 + srk) * 8 + b) * 512 + sck;
    const int srq = t >> 4;            // 0..15
    const int scq = (t & 15) * 4;      // 0..60
    const float* eq_src = eq + ((size_t)(q0b + srq) * 8 + b) * 512 + scq;

    float4 pk0 = *(const float4*)&ek_src[0];
    float4 pk1 = *(const float4*)&ek_src[4];
    float4 pq0 = *(const float4*)&eq_src[0];

    *(float2*)&kb[0][srk][sck + 0] = {pk0.x, pk0.y};
    *(float2*)&kb[0][srk][sck + 2] = {pk0.z, pk0.w};
    *(float2*)&kb[0][srk][sck + 4] = {pk1.x, pk1.y};
    *(float2*)&kb[0][srk][sck + 6] = {pk1.z, pk1.w};
    *(float2*)&qb[0][srq][scq + 0] = {pq0.x, pq0.y};
    *(float2*)&qb[0][srq][scq + 2] = {pq0.z, pq0.w};
    __syncthreads();

    float racc[4] = {0.f, 0.f, 0.f, 0.f};

    for (int chunk = 0; chunk < 8; ++chunk) {
        const int buf = chunk & 1;
        const int hc = chunk * 64;
        if (chunk < 7) {
            pk0 = *(const float4*)&ek_src[hc + 64];
            pk1 = *(const float4*)&ek_src[hc + 68];
            pq0 = *(const float4*)&eq_src[hc + 64];
        }
        #pragma unroll
        for (int s = 0; s < 16; ++s) {
            const float2 e01 = *(const float2*)&kb[buf][kk][4 * s + 2 * p];
            const float2 w01 = *(const float2*)&w2s[hc + 4 * s + 2 * p];
            const float wsum = w01.x + w01.y;
            #pragma unroll
            for (int qi = 0; qi < 4; ++qi) {
                const float2 g01 = *(const float2*)&qb[buf][wave * 4 + qi][4 * s + 2 * p];
                const float t0 = e01.x * g01.x;
                const float t1 = e01.y * g01.y;
                const float a   = fmaf(t0, t1, t0);
                const float bb1 = t1 + 1.0f;
                const float den = a + bb1;
                const float num = fmaf(w01.x, t1, fmaf(w01.y, t0, wsum));
                racc[qi] = fmaf(num, frcp(den), racc[qi]);
            }
        }
        __syncthreads();
        if (chunk < 7) {
            const int nb = buf ^ 1;
            *(float2*)&kb[nb][srk][sck + 0] = {pk0.x, pk0.y};
            *(float2*)&kb[nb][srk][sck + 2] = {pk0.z, pk0.w};
            *(float2*)&kb[nb][srk][sck + 4] = {pk1.x, pk1.y};
            *(float2*)&kb[nb][srk][sck + 6] = {pk1.z, pk1.w};
            *(float2*)&qb[nb][srq][scq + 0] = {pq0.x, pq0.y};
            *(float2*)&qb[nb][srq][scq + 2] = {pq0.z, pq0.w};
        }
        __syncthreads();
    }

    const int kglob = k0 + kk;
    const int msk = mask[kglob * 8 + b];
    #pragma unroll
    for (int qi = 0; qi < 4; ++qi) {
        float r = racc[qi] + __shfl_xor(racc[qi], 1, 64);
        float sc = base - 2.0f * r;
        if (msk) sc = -INFINITY;
        if (p == 0)
            score[((size_t)(q0b + wave * 4 + qi) * 8 + b) * 256 + kglob] = sc;
    }
}

// ---------------------------------------------------------------------------
// Kernel 3: fused softmax + ant_vec. Block (4 q, 1 b), 256 thr.
// Wave w: softmax of q=qt*4+w over 256 k (shuffle-reduce), probs -> LDS +
// scattered prob_out. Then thread owns 2 h, loops k with LDS-broadcast probs.
// ---------------------------------------------------------------------------
__global__ __launch_bounds__(256) void smav_kernel(
    const float* __restrict__ score, const float* __restrict__ ckey,
    float* __restrict__ prob_out, float* __restrict__ out_ant)
{
    const int qt = blockIdx.x;     // 32
    const int b  = blockIdx.y;     // 8
    const int t  = threadIdx.x;
    const int wave = t >> 6, lane = t & 63;
    const int q  = qt * 4 + wave;
    const int qb_idx = q * 8 + b;

    __shared__ float p_lds[4][256];

    float4 s4 = *(const float4*)&score[(size_t)qb_idx * 256 + lane * 4];
    float m = fmaxf(fmaxf(s4.x, s4.y), fmaxf(s4.z, s4.w));
    #pragma unroll
    for (int d = 32; d; d >>= 1) m = fmaxf(m, __shfl_xor(m, d, 64));

    float4 pv;
    pv.x = fexp2((s4.x - m) * L2E);
    pv.y = fexp2((s4.y - m) * L2E);
    pv.z = fexp2((s4.z - m) * L2E);
    pv.w = fexp2((s4.w - m) * L2E);
    float sum = pv.x + pv.y + pv.z + pv.w;
    #pragma unroll
    for (int d = 32; d; d >>= 1) sum += __shfl_xor(sum, d, 64);
    const float inv = frcp(sum);
    pv.x *= inv; pv.y *= inv; pv.z *= inv; pv.w *= inv;

    *(float4*)&p_lds[wave][lane * 4] = pv;
    const int kbase = lane * 4;
    prob_out[(size_t)(kbase + 0) * 1024 + qb_idx] = pv.x;
    prob_out[(size_t)(kbase + 1) * 1024 + qb_idx] = pv.y;
    prob_out[(size_t)(kbase + 2) * 1024 + qb_idx] = pv.z;
    prob_out[(size_t)(kbase + 3) * 1024 + qb_idx] = pv.w;
    __syncthreads();

    const int h2 = t * 2;
    float2 acc[4] = {{0.f,0.f},{0.f,0.f},{0.f,0.f},{0.f,0.f}};
    #pragma unroll 4
    for (int k = 0; k < 256; ++k) {
        const float2 ck = *(const float2*)&ckey[((size_t)k * 8 + b) * 512 + h2];
        #pragma unroll
        for (int qi = 0; qi < 4; ++qi) {
            const float pq = p_lds[qi][k];
            acc[qi].x = fmaf(pq, ck.x, acc[qi].x);
            acc[qi].y = fmaf(pq, ck.y, acc[qi].y);
        }
    }
    #pragma unroll
    for (int qi = 0; qi < 4; ++qi)
        *(float2*)&out_ant[((size_t)(qt * 4 + qi) * 8 + b) * 512 + h2] = acc[qi];
}

// ---------------------------------------------------------------------------
extern "C" void kernel_launch(void* const* d_in, const int* in_sizes, int n_in,
                              void* d_out, int out_size, void* d_ws, size_t ws_size,
                              hipStream_t stream)
{
    const float* qry  = (const float*)d_in[0];   // [128][8][512]
    const float* ckey = (const float*)d_in[1];   // [256][8][512]
    const int*   mask = (const int*)d_in[2];     // [256][8]
    const float* W1   = (const float*)d_in[3];   // [1024][512]
    const float* b1   = (const float*)d_in[4];   // [512]
    const float* W2   = (const float*)d_in[5];   // [512]
    const float* b2   = (const float*)d_in[6];   // [1]

    float* out_ant  = (float*)d_out;                      // [128][8][512]
    float* out_prob = (float*)d_out + T_Q * BB * NHID;    // [256][128][8]

    float* ws = (float*)d_ws;
    float* ws_ek = ws;                                        // [2048][512] f32, 4MB
    float* ws_eq = ws + 1048576;                              // [1024][512] f32, 2MB
    unsigned short* bt_hi = (unsigned short*)(ws + 1572864);  // [1024][512] bf16, 1MB
    unsigned short* bt_lo = (unsigned short*)(ws + 1835008);  // 1MB
    float* ws_sc = ws + 2097152;                              // [1024][256] f32, 1MB

    convert_w1_kernel<<<dim3(128), 256, 0, stream>>>(W1, bt_hi, bt_lo);
    proj_kernel<<<dim3(48, 8), 256, 0, stream>>>(qry, ckey, bt_hi, bt_lo, b1, ws_ek, ws_eq);
    score_kernel<<<dim3(8, 8, 8), 256, 0, stream>>>(ws_ek, ws_eq, W2, b2, mask, ws_sc);
    smav_kernel<<<dim3(32, 8), 256, 0, stream>>>(ws_sc, ckey, out_prob, out_ant);
}

// Round 5
// 124.392 us; speedup vs baseline: 1.5770x; 1.0834x over previous
//
#include <hip/hip_runtime.h>
#include <math.h>

#define NHID 512
#define T_K  256
#define T_Q  128
#define BB   8

// tanh(x) = 1 - 2/(exp2(C*x)+1), C = 2*log2(e)
constexpr float C2L2E = 2.8853900817779268f;
constexpr float L2E   = 1.4426950408889634f;

__device__ __forceinline__ float fexp2(float x) { return __builtin_amdgcn_exp2f(x); }
__device__ __forceinline__ float frcp(float x)  { return __builtin_amdgcn_rcpf(x); }

typedef __attribute__((ext_vector_type(8))) short bf16x8;
typedef __attribute__((ext_vector_type(4))) float f32x4;

__device__ __forceinline__ unsigned short f2bf(float x) {
    unsigned u = __builtin_bit_cast(unsigned, x);
    unsigned r = (u + 0x7FFFu + ((u >> 16) & 1u)) >> 16;
    return (unsigned short)r;
}
__device__ __forceinline__ float bf2f(unsigned short h) {
    unsigned u = ((unsigned)h) << 16;
    return __builtin_bit_cast(float, u);
}

// ---------------------------------------------------------------------------
// Kernel 0: W1 -> BT_hi/lo (split bf16, transposed). 128 blocks. (unchanged)
// ---------------------------------------------------------------------------
__global__ __launch_bounds__(256) void convert_w1_kernel(
    const float* __restrict__ W1,
    unsigned short* __restrict__ bt_hi, unsigned short* __restrict__ bt_lo)
{
    const int tb = blockIdx.x;   // 0..127
    const int kt = tb & 15;
    const int nt = tb >> 4;
    __shared__ float tile[64][65];
    const int t  = threadIdx.x;
    const int r  = t >> 2;
    const int c0 = (t & 3) * 16;
    const float* src = W1 + (size_t)(kt * 64 + r) * 512 + nt * 64 + c0;
    #pragma unroll
    for (int j = 0; j < 4; ++j) {
        const float4 v = *(const float4*)&src[j * 4];
        tile[r][c0 + j * 4 + 0] = v.x; tile[r][c0 + j * 4 + 1] = v.y;
        tile[r][c0 + j * 4 + 2] = v.z; tile[r][c0 + j * 4 + 3] = v.w;
    }
    __syncthreads();
    const size_t dst = (size_t)((kt >> 3) * 512 + nt * 64 + r) * 512
                     + (size_t)((kt & 7) * 64 + c0);
    #pragma unroll
    for (int j4 = 0; j4 < 4; ++j4) {
        ushort4 h, l;
        #pragma unroll
        for (int e = 0; e < 4; ++e) {
            const float x = tile[c0 + j4 * 4 + e][r];
            const unsigned short hb = f2bf(x);
            const unsigned short lb = f2bf(x - bf2f(hb));
            ((unsigned short*)&h)[e] = hb;
            ((unsigned short*)&l)[e] = lb;
        }
        *(ushort4*)&bt_hi[dst + j4 * 4] = h;
        *(ushort4*)&bt_lo[dst + j4 * 4] = l;
    }
}

// ---------------------------------------------------------------------------
// Kernel 1: proj GEMM, split-bf16 MFMA; epilogue stores ek=exp2(.), eq=exp2(.)
// (unchanged from R4)
// ---------------------------------------------------------------------------
__global__ __launch_bounds__(256) void proj_kernel(
    const float* __restrict__ qry, const float* __restrict__ ckey,
    const unsigned short* __restrict__ bt_hi, const unsigned short* __restrict__ bt_lo,
    const float* __restrict__ b1,
    float* __restrict__ ek, float* __restrict__ eq)
{
    const int row0 = blockIdx.x * 64;
    const int col0 = blockIdx.y * 64;
    const bool isK = row0 < 2048;
    const int bhalf = isK ? 0 : 512;

    __shared__ __align__(16) unsigned short As_h[64 * 64];
    __shared__ __align__(16) unsigned short As_l[64 * 64];
    __shared__ __align__(16) unsigned short Bs_h[64 * 64];
    __shared__ __align__(16) unsigned short Bs_l[64 * 64];

    const int t    = threadIdx.x;
    const int wave = t >> 6;
    const int lane = t & 63;
    const int wm = (wave & 1) * 32;
    const int wn = (wave >> 1) * 32;

    f32x4 acc[2][2] = {};

    const int sr = t >> 2;
    const int sc = (t & 3) * 16;
    const float* gA = (isK ? ckey + (size_t)(row0 + sr) * 512
                           : qry  + (size_t)(row0 - 2048 + sr) * 512) + sc;
    const unsigned short* gBh = bt_hi + (size_t)(bhalf + col0 + sr) * 512 + sc;
    const unsigned short* gBl = bt_lo + (size_t)(bhalf + col0 + sr) * 512 + sc;
    const int c0c = sc >> 3;
    const int sw0 = ((c0c + 0) ^ (sr & 7)) * 8;
    const int sw1 = ((c0c + 1) ^ (sr & 7)) * 8;

    const int quad = lane >> 4, fr = lane & 15;

    for (int k0 = 0; k0 < 512; k0 += 64) {
        __syncthreads();
        {
            float fa[16];
            *(float4*)&fa[0]  = *(const float4*)&gA[k0 + 0];
            *(float4*)&fa[4]  = *(const float4*)&gA[k0 + 4];
            *(float4*)&fa[8]  = *(const float4*)&gA[k0 + 8];
            *(float4*)&fa[12] = *(const float4*)&gA[k0 + 12];
            union { uint4 v; unsigned short s[8]; } h0, l0, h1, l1;
            #pragma unroll
            for (int e = 0; e < 8; ++e) {
                const unsigned short hb = f2bf(fa[e]);
                h0.s[e] = hb; l0.s[e] = f2bf(fa[e] - bf2f(hb));
            }
            #pragma unroll
            for (int e = 0; e < 8; ++e) {
                const unsigned short hb = f2bf(fa[8 + e]);
                h1.s[e] = hb; l1.s[e] = f2bf(fa[8 + e] - bf2f(hb));
            }
            *(uint4*)&As_h[sr * 64 + sw0] = h0.v; *(uint4*)&As_h[sr * 64 + sw1] = h1.v;
            *(uint4*)&As_l[sr * 64 + sw0] = l0.v; *(uint4*)&As_l[sr * 64 + sw1] = l1.v;
            uint4 v0, v1;
            v0 = *(const uint4*)&gBh[k0];     v1 = *(const uint4*)&gBh[k0 + 8];
            *(uint4*)&Bs_h[sr * 64 + sw0] = v0; *(uint4*)&Bs_h[sr * 64 + sw1] = v1;
            v0 = *(const uint4*)&gBl[k0];     v1 = *(const uint4*)&gBl[k0 + 8];
            *(uint4*)&Bs_l[sr * 64 + sw0] = v0; *(uint4*)&Bs_l[sr * 64 + sw1] = v1;
        }
        __syncthreads();
        #pragma unroll
        for (int ks = 0; ks < 2; ++ks) {
            const int cchunk = ks * 4 + quad;
            bf16x8 afh[2], afl[2], bfh[2], bfl[2];
            #pragma unroll
            for (int mt = 0; mt < 2; ++mt) {
                const int m = wm + mt * 16 + fr;
                afh[mt] = *(const bf16x8*)&As_h[m * 64 + ((cchunk ^ (m & 7)) * 8)];
                afl[mt] = *(const bf16x8*)&As_l[m * 64 + ((cchunk ^ (m & 7)) * 8)];
            }
            #pragma unroll
            for (int nt = 0; nt < 2; ++nt) {
                const int n = wn + nt * 16 + fr;
                bfh[nt] = *(const bf16x8*)&Bs_h[n * 64 + ((cchunk ^ (n & 7)) * 8)];
                bfl[nt] = *(const bf16x8*)&Bs_l[n * 64 + ((cchunk ^ (n & 7)) * 8)];
            }
            #pragma unroll
            for (int mt = 0; mt < 2; ++mt)
                #pragma unroll
                for (int nt = 0; nt < 2; ++nt) {
                    acc[mt][nt] = __builtin_amdgcn_mfma_f32_16x16x32_bf16(afh[mt], bfh[nt], acc[mt][nt], 0, 0, 0);
                    acc[mt][nt] = __builtin_amdgcn_mfma_f32_16x16x32_bf16(afh[mt], bfl[nt], acc[mt][nt], 0, 0, 0);
                    acc[mt][nt] = __builtin_amdgcn_mfma_f32_16x16x32_bf16(afl[mt], bfh[nt], acc[mt][nt], 0, 0, 0);
                }
        }
    }

    #pragma unroll
    for (int nt = 0; nt < 2; ++nt) {
        const int colg = col0 + wn + nt * 16 + fr;
        const float b1v = b1[colg];
        #pragma unroll
        for (int mt = 0; mt < 2; ++mt) {
            #pragma unroll
            for (int i = 0; i < 4; ++i) {
                const int rowg = row0 + wm + mt * 16 + quad * 4 + i;
                const float v = acc[mt][nt][i];
                if (isK) ek[(size_t)rowg * 512 + colg] = fexp2((v + b1v) * C2L2E);
                else     eq[(size_t)(rowg - 2048) * 512 + colg] = fexp2(v * C2L2E);
            }
        }
    }
}

// ---------------------------------------------------------------------------
// Kernel 2: score. Grid (8 kt, 16 qt, 8 b) = 1024 blocks -> 4 blocks/CU.
// Block: 32 k x 8 q; wave -> 2 q; lane = (kk = lane>>1, p = lane&1).
// Same exp2-factorized math: 0.5 rcp + ~9 VALU per 2 elems.
// ---------------------------------------------------------------------------
__global__ __launch_bounds__(256) void score_kernel(
    const float* __restrict__ ek, const float* __restrict__ eq,
    const float* __restrict__ W2, const float* __restrict__ b2,
    const int* __restrict__ mask, float* __restrict__ score)
{
    const int t    = threadIdx.x;
    const int wave = __builtin_amdgcn_readfirstlane(t >> 6);
    const int lane = t & 63;
    const int kk = lane >> 1;
    const int p  = lane & 1;
    const int k0 = blockIdx.x * 32;
    const int q0 = blockIdx.y * 8;
    const int b  = blockIdx.z;

    __shared__ float kb[2][32][66];
    __shared__ float qb[2][8][66];
    __shared__ float w2s[512];

    *(float2*)&w2s[t * 2] = *(const float2*)&W2[t * 2];

    // base = sum(W2) + b2
    const float4 wA = *(const float4*)&W2[lane * 4];
    const float4 wB = *(const float4*)&W2[256 + lane * 4];
    float s2 = wA.x + wA.y + wA.z + wA.w + wB.x + wB.y + wB.z + wB.w;
    #pragma unroll
    for (int m = 32; m; m >>= 1) s2 += __shfl_xor(s2, m, 64);
    const float base = s2 + b2[0];

    // staging maps
    const int srk = t >> 3;            // 0..31
    const int sck = (t & 7) * 8;       // 0..56
    const float* ek_src = ek + ((size_t)(k0 + srk) * 8 + b) * 512 + sck;
    const int srq = t >> 5;            // 0..7
    const int scq = (t & 31) * 2;      // 0..62
    const float* eq_src = eq + ((size_t)(q0 + srq) * 8 + b) * 512 + scq;

    float4 pk0 = *(const float4*)&ek_src[0];
    float4 pk1 = *(const float4*)&ek_src[4];
    float2 pq0 = *(const float2*)&eq_src[0];

    *(float2*)&kb[0][srk][sck + 0] = {pk0.x, pk0.y};
    *(float2*)&kb[0][srk][sck + 2] = {pk0.z, pk0.w};
    *(float2*)&kb[0][srk][sck + 4] = {pk1.x, pk1.y};
    *(float2*)&kb[0][srk][sck + 6] = {pk1.z, pk1.w};
    *(float2*)&qb[0][srq][scq] = pq0;
    __syncthreads();

    float racc[2] = {0.f, 0.f};

    for (int chunk = 0; chunk < 8; ++chunk) {
        const int buf = chunk & 1;
        const int hc = chunk * 64;
        if (chunk < 7) {
            pk0 = *(const float4*)&ek_src[hc + 64];
            pk1 = *(const float4*)&ek_src[hc + 68];
            pq0 = *(const float2*)&eq_src[hc + 64];
        }
        #pragma unroll
        for (int s = 0; s < 16; ++s) {
            const float2 e01 = *(const float2*)&kb[buf][kk][4 * s + 2 * p];
            const float2 w01 = *(const float2*)&w2s[hc + 4 * s + 2 * p];
            const float wsum = w01.x + w01.y;
            #pragma unroll
            for (int qi = 0; qi < 2; ++qi) {
                const float2 g01 = *(const float2*)&qb[buf][wave * 2 + qi][4 * s + 2 * p];
                const float t0 = e01.x * g01.x;
                const float t1 = e01.y * g01.y;
                const float a   = fmaf(t0, t1, t0);
                const float bb1 = t1 + 1.0f;
                const float den = a + bb1;
                const float num = fmaf(w01.x, t1, fmaf(w01.y, t0, wsum));
                racc[qi] = fmaf(num, frcp(den), racc[qi]);
            }
        }
        __syncthreads();
        if (chunk < 7) {
            const int nb = buf ^ 1;
            *(float2*)&kb[nb][srk][sck + 0] = {pk0.x, pk0.y};
            *(float2*)&kb[nb][srk][sck + 2] = {pk0.z, pk0.w};
            *(float2*)&kb[nb][srk][sck + 4] = {pk1.x, pk1.y};
            *(float2*)&kb[nb][srk][sck + 6] = {pk1.z, pk1.w};
            *(float2*)&qb[nb][srq][scq] = pq0;
        }
        __syncthreads();
    }

    const int kglob = k0 + kk;
    const int msk = mask[kglob * 8 + b];
    #pragma unroll
    for (int qi = 0; qi < 2; ++qi) {
        float r = racc[qi] + __shfl_xor(racc[qi], 1, 64);
        float sc = base - 2.0f * r;
        if (msk) sc = -INFINITY;
        if (p == 0)
            score[((size_t)(q0 + wave * 2 + qi) * 8 + b) * 256 + kglob] = sc;
    }
}

// ---------------------------------------------------------------------------
// Kernel 3: fused softmax + ant_vec, wave-k-split.
// Phase 1 (softmax): wave w handles q=qt*4+w over 256 k -> p_lds[w][256].
// Phase 2 (antvec): wave w handles k in [w*64, w*64+64); lane owns 8 h
// (2x b128 ckey loads per k); partials -> LDS; phase 3 combines 4 partials.
// ---------------------------------------------------------------------------
__global__ __launch_bounds__(256) void smav_kernel(
    const float* __restrict__ score, const float* __restrict__ ckey,
    float* __restrict__ prob_out, float* __restrict__ out_ant)
{
    const int qt = blockIdx.x;     // 32
    const int b  = blockIdx.y;     // 8
    const int t  = threadIdx.x;
    const int wave = __builtin_amdgcn_readfirstlane(t >> 6);
    const int lane = t & 63;
    const int q  = qt * 4 + wave;
    const int qb_idx = q * 8 + b;

    __shared__ float p_lds[4][256];
    __shared__ float pacc[4][4][512];   // [wave][q][h]

    // ---- softmax (wave per q) ----
    float4 s4 = *(const float4*)&score[(size_t)qb_idx * 256 + lane * 4];
    float m = fmaxf(fmaxf(s4.x, s4.y), fmaxf(s4.z, s4.w));
    #pragma unroll
    for (int d = 32; d; d >>= 1) m = fmaxf(m, __shfl_xor(m, d, 64));

    float4 pv;
    pv.x = fexp2((s4.x - m) * L2E);
    pv.y = fexp2((s4.y - m) * L2E);
    pv.z = fexp2((s4.z - m) * L2E);
    pv.w = fexp2((s4.w - m) * L2E);
    float sum = pv.x + pv.y + pv.z + pv.w;
    #pragma unroll
    for (int d = 32; d; d >>= 1) sum += __shfl_xor(sum, d, 64);
    const float inv = frcp(sum);
    pv.x *= inv; pv.y *= inv; pv.z *= inv; pv.w *= inv;

    *(float4*)&p_lds[wave][lane * 4] = pv;
    const int kbase = lane * 4;
    prob_out[(size_t)(kbase + 0) * 1024 + qb_idx] = pv.x;
    prob_out[(size_t)(kbase + 1) * 1024 + qb_idx] = pv.y;
    prob_out[(size_t)(kbase + 2) * 1024 + qb_idx] = pv.z;
    prob_out[(size_t)(kbase + 3) * 1024 + qb_idx] = pv.w;
    __syncthreads();

    // ---- antvec partials: wave owns k-range, lane owns 8 h ----
    const int h0 = lane * 8;
    float4 accL[4] = {}, accH[4] = {};
    const int kstart = wave * 64;
    #pragma unroll 4
    for (int ki = 0; ki < 64; ++ki) {
        const int k = kstart + ki;
        const float* ckp = &ckey[((size_t)k * 8 + b) * 512 + h0];
        const float4 c0 = *(const float4*)&ckp[0];
        const float4 c1 = *(const float4*)&ckp[4];
        #pragma unroll
        for (int qi = 0; qi < 4; ++qi) {
            const float pq = p_lds[qi][k];
            accL[qi].x = fmaf(pq, c0.x, accL[qi].x);
            accL[qi].y = fmaf(pq, c0.y, accL[qi].y);
            accL[qi].z = fmaf(pq, c0.z, accL[qi].z);
            accL[qi].w = fmaf(pq, c0.w, accL[qi].w);
            accH[qi].x = fmaf(pq, c1.x, accH[qi].x);
            accH[qi].y = fmaf(pq, c1.y, accH[qi].y);
            accH[qi].z = fmaf(pq, c1.z, accH[qi].z);
            accH[qi].w = fmaf(pq, c1.w, accH[qi].w);
        }
    }
    #pragma unroll
    for (int qi = 0; qi < 4; ++qi) {
        *(float4*)&pacc[wave][qi][h0 + 0] = accL[qi];
        *(float4*)&pacc[wave][qi][h0 + 4] = accH[qi];
    }
    __syncthreads();

    // ---- combine: thread t owns h2 = t*2 ----
    const int h2 = t * 2;
    #pragma unroll
    for (int qi = 0; qi < 4; ++qi) {
        float2 r0 = *(const float2*)&pacc[0][qi][h2];
        float2 r1 = *(const float2*)&pacc[1][qi][h2];
        float2 r2 = *(const float2*)&pacc[2][qi][h2];
        float2 r3 = *(const float2*)&pacc[3][qi][h2];
        float2 r;
        r.x = (r0.x + r1.x) + (r2.x + r3.x);
        r.y = (r0.y + r1.y) + (r2.y + r3.y);
        *(float2*)&out_ant[((size_t)(qt * 4 + qi) * 8 + b) * 512 + h2] = r;
    }
}

// ---------------------------------------------------------------------------
extern "C" void kernel_launch(void* const* d_in, const int* in_sizes, int n_in,
                              void* d_out, int out_size, void* d_ws, size_t ws_size,
                              hipStream_t stream)
{
    const float* qry  = (const float*)d_in[0];   // [128][8][512]
    const float* ckey = (const float*)d_in[1];   // [256][8][512]
    const int*   mask = (const int*)d_in[2];     // [256][8]
    const float* W1   = (const float*)d_in[3];   // [1024][512]
    const float* b1   = (const float*)d_in[4];   // [512]
    const float* W2   = (const float*)d_in[5];   // [512]
    const float* b2   = (const float*)d_in[6];   // [1]

    float* out_ant  = (float*)d_out;                      // [128][8][512]
    float* out_prob = (float*)d_out + T_Q * BB * NHID;    // [256][128][8]

    float* ws = (float*)d_ws;
    float* ws_ek = ws;                                        // [2048][512] f32, 4MB
    float* ws_eq = ws + 1048576;                              // [1024][512] f32, 2MB
    unsigned short* bt_hi = (unsigned short*)(ws + 1572864);  // [1024][512] bf16, 1MB
    unsigned short* bt_lo = (unsigned short*)(ws + 1835008);  // 1MB
    float* ws_sc = ws + 2097152;                              // [1024][256] f32, 1MB

    convert_w1_kernel<<<dim3(128), 256, 0, stream>>>(W1, bt_hi, bt_lo);
    proj_kernel<<<dim3(48, 8), 256, 0, stream>>>(qry, ckey, bt_hi, bt_lo, b1, ws_ek, ws_eq);
    score_kernel<<<dim3(8, 16, 8), 256, 0, stream>>>(ws_ek, ws_eq, W2, b2, mask, ws_sc);
    smav_kernel<<<dim3(32, 8), 256, 0, stream>>>(ws_sc, ckey, out_prob, out_ant);
}